// Round 2
// baseline (1459.927 us; speedup 1.0000x reference)
//
#include <hip/hip_runtime.h>
#include <hip/hip_bf16.h>
#include <math.h>

// EfficientMambaAttention pipeline, round 2: all inputs/outputs are FLOAT32
// (per reference setup_inputs dtype=jnp.float32). Round-1 NaN was fp32 data
// read as bf16. Structure: final adjust-conv is a per-(b,h) matmul over
// rank-1 fields, so the 8x256x160x160 concat is never materialized.
// All intermediates fp32 in d_ws (~20.2 MB).

__device__ __forceinline__ float sigm_(float x){ return 1.f/(1.f+__expf(-x)); }
__device__ __forceinline__ float silu_(float x){ return x/(1.f+__expf(-x)); }
__device__ __forceinline__ float gelu_(float x){ return 0.5f*x*(1.f+erff(x*0.7071067811865476f)); }
__device__ __forceinline__ float softplus_(float x){ return (x>20.f)?x:log1pf(__expf(x)); }

// K1: row means (over w) -> xh[b,c,h]; col means (over h) -> xw[b,c,w]
__global__ void k_means(const float* __restrict__ x, float* __restrict__ xh, float* __restrict__ xw){
  int bc = blockIdx.x;                    // b*128+c
  const float* xt = x + (size_t)bc*25600; // 160*160 tile
  int tid = threadIdx.x, wave = tid>>6, lane = tid&63;
  __shared__ float colpart[4][160];
  float cs0=0.f, cs1=0.f, cs2=0.f;
  for (int i=0;i<40;i++){
    int h = wave*40+i;
    const float* row = xt + h*160;
    float v0 = row[lane];
    float v1 = row[64+lane];
    float v2 = (lane<32)? row[128+lane] : 0.f;
    cs0+=v0; cs1+=v1; cs2+=v2;
    float r = v0+v1+v2;
    for (int off=32; off>0; off>>=1) r += __shfl_down(r, off, 64);
    if (lane==0) xh[bc*160+h] = r*(1.f/160.f);
  }
  colpart[wave][lane]    = cs0;
  colpart[wave][64+lane] = cs1;
  if (lane<32) colpart[wave][128+lane] = cs2;
  __syncthreads();
  if (tid<160){
    float s = colpart[0][tid]+colpart[1][tid]+colpart[2][tid]+colpart[3][tid];
    xw[bc*160+tid] = s*(1.f/160.f);
  }
}

// K2a: y trunk: conv1x1(C->8) + BN + gelu over p in [0,320)
__global__ void k_ybranch(const float* __restrict__ xh, const float* __restrict__ xw,
                          const float* __restrict__ w1, const float* __restrict__ b1,
                          const float* __restrict__ bg, const float* __restrict__ bb,
                          const float* __restrict__ bm, const float* __restrict__ bv,
                          float* __restrict__ ybuf){
  int gid = blockIdx.x*blockDim.x + threadIdx.x;
  if (gid >= 8*320) return;
  int b = gid/320, p = gid%320;
  const float* in = (p<160) ? (xh + (size_t)b*128*160 + p) : (xw + (size_t)b*128*160 + (p-160));
  float acc[8] = {0,0,0,0,0,0,0,0};
  for (int c=0;c<128;c++){
    float u = in[c*160];
    #pragma unroll
    for (int m=0;m<8;m++) acc[m] += w1[m*128+c]*u;
  }
  #pragma unroll
  for (int m=0;m<8;m++){
    float val = acc[m] + b1[m];
    val = (val - bm[m]) * rsqrtf(bv[m] + 1e-5f);
    val = val * bg[m] + bb[m];
    ybuf[(b*320+p)*8+m] = gelu_(val);
  }
}

// K2b: a_h[b,c,h], a_w[b,c,w]: conv1x1(8->C)
__global__ void k_ahw(const float* __restrict__ ybuf,
                      const float* __restrict__ wh, const float* __restrict__ bh,
                      const float* __restrict__ ww, const float* __restrict__ bw,
                      float* __restrict__ a_h, float* __restrict__ a_w){
  int gid = blockIdx.x*blockDim.x + threadIdx.x;
  if (gid >= 8*128*320) return;
  int p = gid%320; int c = (gid/320)%128; int b = gid/(320*128);
  const float* yv = ybuf + (size_t)(b*320+p)*8;
  const float* w = (p<160)? (wh + c*8) : (ww + c*8);
  float acc = (p<160)? bh[c] : bw[c];
  #pragma unroll
  for (int m=0;m<8;m++) acc += w[m]*yv[m];
  if (p<160) a_h[((size_t)(b*128+c))*160+p] = acc;
  else       a_w[((size_t)(b*128+c))*160+(p-160)] = acc;
}

// K3: mamba in-proj: xz[g,b,l,e] = sum_c u*in_w; e<256 -> xc_pre, else z
__global__ void k_inproj(const float* __restrict__ xh, const float* __restrict__ xw,
                         const float* __restrict__ inw0, const float* __restrict__ inw1,
                         float* __restrict__ xcpre, float* __restrict__ zb){
  int blk = blockIdx.x;                   // (g*8+b)*160 + l
  int g = blk/1280, rem = blk%1280, b = rem/160, l = rem%160;
  __shared__ float u[128];
  const float* src = (g==0)? xh : xw;
  if (threadIdx.x<128) u[threadIdx.x] = src[((size_t)(b*128+threadIdx.x))*160 + l];
  __syncthreads();
  const float* inw = (g==0)? inw0 : inw1;
  size_t outbase = (size_t)blk*256;
  for (int e = threadIdx.x; e < 512; e += 256){
    const float* wr = inw + e*128;
    float acc = 0.f;
    for (int c=0;c<128;c++) acc += wr[c]*u[c];
    if (e<256) xcpre[outbase+e] = acc;
    else       zb[outbase+e-256] = acc;
  }
}

// K4a: depthwise causal conv(k=4) + bias + silu
__global__ void k_conv(const float* __restrict__ xcpre,
                       const float* __restrict__ cw0, const float* __restrict__ cb0,
                       const float* __restrict__ cw1, const float* __restrict__ cb1,
                       float* __restrict__ xcb){
  int gid = blockIdx.x*blockDim.x + threadIdx.x;
  if (gid >= 2*8*160*256) return;
  int d = gid & 255; int t = gid >> 8; int l = t % 160; int gb = t / 160; int g = gb >> 3;
  const float* cw = ((g==0)? cw0 : cw1) + d*4;
  float acc = ((g==0)? cb0 : cb1)[d];
  const float* base = xcpre + (size_t)gb*160*256 + d;
  #pragma unroll
  for (int k=0;k<4;k++){
    int ls = l-3+k;
    if (ls>=0) acc += cw[k] * base[(size_t)ls*256];
  }
  xcb[gid] = silu_(acc);
}

// K4b: x-proj: dbc[g,b,l,j<40] = sum_d xc * xproj[j,d]
__global__ void k_xproj(const float* __restrict__ xcb,
                        const float* __restrict__ xp0, const float* __restrict__ xp1,
                        float* __restrict__ dbc){
  int blk = blockIdx.x;                   // (g*8+b)*160 + l
  int g = blk/1280;
  __shared__ float xv[256];
  const float* src = xcb + (size_t)blk*256;
  for (int i=threadIdx.x;i<256;i+=64) xv[i] = src[i];
  __syncthreads();
  int j = threadIdx.x;
  if (j < 40){
    const float* w = ((g==0)? xp0 : xp1) + j*256;
    float acc = 0.f;
    for (int d=0;d<256;d++) acc += w[d]*xv[d];
    dbc[(size_t)blk*40 + j] = acc;
  }
}

// K4c: delta = softplus(dt @ dt_w^T + dt_b)
__global__ void k_delta(const float* __restrict__ dbc,
                        const float* __restrict__ dtw0, const float* __restrict__ dtb0,
                        const float* __restrict__ dtw1, const float* __restrict__ dtb1,
                        float* __restrict__ delta){
  int gid = blockIdx.x*blockDim.x + threadIdx.x;
  if (gid >= 2*8*160*256) return;
  int d = gid & 255; int t = gid >> 8; int gb = t/160; int g = gb>>3;
  const float* dv = dbc + (size_t)t*40;
  const float* w = ((g==0)? dtw0 : dtw1) + d*8;
  float acc = ((g==0)? dtb0 : dtb1)[d];
  #pragma unroll
  for (int r=0;r<8;r++) acc += w[r]*dv[r];
  delta[gid] = softplus_(acc);
}

// K5: selective scan. 16 lanes per d (one per state n).
__global__ void k_scan(const float* __restrict__ delta, const float* __restrict__ dbc,
                       const float* __restrict__ xcb, const float* __restrict__ zb,
                       const float* __restrict__ Alog0, const float* __restrict__ Alog1,
                       const float* __restrict__ D0, const float* __restrict__ D1,
                       float* __restrict__ ysb){
  int blk = blockIdx.x;        // 256 blocks: gb = blk>>4, dblk = blk&15
  int gb = blk >> 4, dblk = blk & 15, g = gb >> 3;
  int tid = threadIdx.x;
  int d = dblk*16 + (tid>>4);
  int n = tid & 15;
  const float* Alog = g? Alog1 : Alog0;
  const float* Dp   = g? D1 : D0;
  float A = -__expf(Alog[d*16+n]);
  float Dd = Dp[d];
  size_t base = (size_t)gb*160*256;
  const float* del = delta + base;
  const float* xc  = xcb + base;
  const float* zz  = zb + base;
  float* ys = ysb + base;
  const float* db = dbc + (size_t)gb*160*40;
  float h = 0.f;
  float dl = del[d], xcv = xc[d], zv = zz[d];
  float Bn = db[8+n], Cn = db[24+n];
  for (int l=0; l<160; l++){
    float dl2=0.f,xcv2=0.f,zv2=0.f,Bn2=0.f,Cn2=0.f;
    if (l<159){
      size_t o = (size_t)(l+1)*256 + d;
      dl2=del[o]; xcv2=xc[o]; zv2=zz[o];
      size_t o2 = (size_t)(l+1)*40;
      Bn2=db[o2+8+n]; Cn2=db[o2+24+n];
    }
    float dA = __expf(dl*A);
    h = dA*h + dl*Bn*xcv;
    float p = h*Cn;
    p += __shfl_xor(p,1,16); p += __shfl_xor(p,2,16);
    p += __shfl_xor(p,4,16); p += __shfl_xor(p,8,16);
    if (n==0){
      float yv = p + xcv*Dd;
      ys[(size_t)l*256+d] = yv * silu_(zv);
    }
    dl=dl2; xcv=xcv2; zv=zv2; Bn=Bn2; Cn=Cn2;
  }
}

// K6a: out-proj (256->128) + add a + sigmoid -> S[g,b,c,l]
__global__ void k_outproj(const float* __restrict__ ysb,
                          const float* __restrict__ ow0, const float* __restrict__ ow1,
                          const float* __restrict__ a_h, const float* __restrict__ a_w,
                          float* __restrict__ S){
  int blk = blockIdx.x;  // (g*8+b)*160 + l
  int g = blk/1280, rem = blk%1280, b = rem/160, l = rem%160;
  __shared__ float yv[256];
  const float* src = ysb + (size_t)blk*256;
  yv[threadIdx.x] = src[threadIdx.x];
  yv[threadIdx.x+128] = src[threadIdx.x+128];
  __syncthreads();
  int c = threadIdx.x;
  const float* w = ((g==0)? ow0 : ow1) + c*256;
  float acc = 0.f;
  for (int d=0;d<256;d++) acc += w[d]*yv[d];
  const float* a = (g==0)? a_h : a_w;
  float val = sigm_(acc + a[((size_t)(b*128+c))*160 + l]);
  S[((size_t)(g*8+b)*128 + c)*160 + l] = val;
}

// K6b: MLP layer1 + gelu -> t1[g,b,p,c]
__global__ void k_mlp1(const float* __restrict__ S,
                       const float* __restrict__ w1x, const float* __restrict__ b1x,
                       const float* __restrict__ w1y, const float* __restrict__ b1y,
                       float* __restrict__ t1){
  int blk = blockIdx.x;  // (g*8+b)*160 + p
  int g = blk/1280, rem = blk%1280, b = rem/160, p = rem%160;
  __shared__ float sv[128];
  sv[threadIdx.x] = S[((size_t)(g*8+b)*128 + threadIdx.x)*160 + p];
  __syncthreads();
  int o = threadIdx.x;
  const float* w = ((g==0)? w1x : w1y) + o*128;
  float acc = ((g==0)? b1x : b1y)[o];
  for (int c=0;c<128;c++) acc += w[c]*sv[c];
  t1[(size_t)blk*128 + o] = gelu_(acc);
}

// K6c: MLP layer2 -> Qx[b,c,h] (g=0), Qy[b,c,w] (g=1)
__global__ void k_mlp2(const float* __restrict__ t1,
                       const float* __restrict__ w2x, const float* __restrict__ b2x,
                       const float* __restrict__ w2y, const float* __restrict__ b2y,
                       float* __restrict__ Qx, float* __restrict__ Qy){
  int blk = blockIdx.x;
  int g = blk/1280, rem = blk%1280, b = rem/160, p = rem%160;
  __shared__ float tv[128];
  tv[threadIdx.x] = t1[(size_t)blk*128 + threadIdx.x];
  __syncthreads();
  int o = threadIdx.x;
  const float* w = ((g==0)? w2x : w2y) + o*128;
  float acc = ((g==0)? b2x : b2y)[o];
  for (int c=0;c<128;c++) acc += w[c]*tv[c];
  float* Q = (g==0)? Qx : Qy;
  Q[((size_t)(b*128+o))*160 + p] = acc;
}

// K7: out[b,o,h,w] = x * ( A1[o,:]·(P[:,h]*Qy[:,w]) + A2[o,:]·(Qx[:,h]*R[:,w]) )
__global__ __launch_bounds__(256) void k_final(const float* __restrict__ x,
                       const float* __restrict__ a_h, const float* __restrict__ a_w,
                       const float* __restrict__ Qx, const float* __restrict__ Qy,
                       const float* __restrict__ adjw, float* __restrict__ out){
  __shared__ float2 f12[128][64];   // .x = P[c,h]*Qy[c,w], .y = Qx[c,h]*R[c,w]  (64KB)
  int blk = blockIdx.x;             // b*160*3 + h*3 + wt
  int wt = blk%3; int bh = blk/3; int h = bh%160; int b = bh/160;
  int wbase = wt*64; int wlen = (wbase+64<=160)? 64 : (160-wbase);
  int tid = threadIdx.x;
  int wloc = tid & 63, q = tid >> 6;
  // fill phase: 4 c-rows per pass
  for (int c = q; c < 128; c += 4){
    float Pv = sigm_(a_h[((size_t)(b*128+c))*160 + h]);
    float Sv = Qx[((size_t)(b*128+c))*160 + h];
    float qv = 0.f, rv = 0.f;
    if (wloc < wlen){
      int w = wbase + wloc;
      qv = Qy[((size_t)(b*128+c))*160 + w];
      rv = sigm_(a_w[((size_t)(b*128+c))*160 + w]);
    }
    f12[c][wloc] = make_float2(Pv*qv, Sv*rv);
  }
  __syncthreads();
  // compute: each thread does 8 o at a time, 4 groups -> 32 o total per q-slice
  for (int og=0; og<4; og++){
    int ob = og*32 + q*8;
    float acc[8] = {0,0,0,0,0,0,0,0};
    for (int c2=0; c2<64; c2++){
      float2 fe = f12[2*c2][wloc];
      float2 fo = f12[2*c2+1][wloc];
      #pragma unroll
      for (int j=0;j<8;j++){
        const float2* a1v = reinterpret_cast<const float2*>(adjw + (ob+j)*256);
        const float2* a2v = reinterpret_cast<const float2*>(adjw + (ob+j)*256 + 128);
        float2 w1 = a1v[c2];
        float2 w2 = a2v[c2];
        acc[j] += w1.x*fe.x + w1.y*fo.x + w2.x*fe.y + w2.y*fo.y;
      }
    }
    if (wloc < wlen){
      #pragma unroll
      for (int j=0;j<8;j++){
        size_t idx = (((size_t)(b*128+ob+j))*160 + h)*160 + wbase + wloc;
        out[idx] = x[idx] * acc[j];
      }
    }
  }
}

extern "C" void kernel_launch(void* const* d_in, const int* in_sizes, int n_in,
                              void* d_out, int out_size, void* d_ws, size_t ws_size,
                              hipStream_t stream) {
  #define W(i) ((const float*)d_in[i])
  const float* X = W(0);
  float* ws = (float*)d_ws;
  float* xh    = ws;               // 163840
  float* xw    = xh    + 163840;   // 163840
  float* ybuf  = xw    + 163840;   // 20480
  float* ah    = ybuf  + 20480;    // 163840
  float* aw    = ah    + 163840;   // 163840
  float* xcpre = aw    + 163840;   // 655360
  float* zb    = xcpre + 655360;   // 655360
  float* xcb   = zb    + 655360;   // 655360
  float* dbc   = xcb   + 655360;   // 102400
  float* delta = dbc   + 102400;   // 655360
  float* ysb   = delta + 655360;   // 655360
  float* S     = ysb   + 655360;   // 327680
  float* t1    = S     + 327680;   // 327680
  float* Qx    = t1    + 327680;   // 163840
  float* Qy    = Qx    + 163840;   // 163840

  k_means  <<<1024, 256, 0, stream>>>(X, xh, xw);
  k_ybranch<<<10,   256, 0, stream>>>(xh, xw, W(1), W(2), W(3), W(4), W(5), W(6), ybuf);
  k_ahw    <<<1280, 256, 0, stream>>>(ybuf, W(7), W(8), W(9), W(10), ah, aw);
  k_inproj <<<2560, 256, 0, stream>>>(xh, xw, W(20), W(29), xcpre, zb);
  k_conv   <<<2560, 256, 0, stream>>>(xcpre, W(21), W(22), W(30), W(31), xcb);
  k_xproj  <<<2560, 64,  0, stream>>>(xcb, W(23), W(32), dbc);
  k_delta  <<<2560, 256, 0, stream>>>(dbc, W(24), W(25), W(33), W(34), delta);
  k_scan   <<<256,  256, 0, stream>>>(delta, dbc, xcb, zb, W(26), W(35), W(27), W(36), ysb);
  k_outproj<<<2560, 128, 0, stream>>>(ysb, W(28), W(37), ah, aw, S);
  k_mlp1   <<<2560, 128, 0, stream>>>(S, W(11), W(12), W(15), W(16), t1);
  k_mlp2   <<<2560, 128, 0, stream>>>(t1, W(13), W(14), W(17), W(18), Qx, Qy);
  k_final  <<<3840, 256, 0, stream>>>(X, ah, aw, Qx, Qy, W(19), (float*)d_out);
  #undef W
}

// Round 3
// 652.279 us; speedup vs baseline: 2.2382x; 2.2382x over previous
//
#include <hip/hip_runtime.h>
#include <hip/hip_bf16.h>
#include <math.h>

// EfficientMambaAttention, round 3: k_final -> MFMA bf16 GEMM.
// out1[b,o,h,w] = sum_k adjw[o,k]*F[k,h,w], F[k<128]=sigm(a_h)*Qy, F[k>=128]=Qx*sigm(a_w).
// Per block (b,h,whalf): F staged bf16 in LDS [80 w][264 k-padded], adjw bf16 A-frags
// register-resident, 16x16x32 bf16 MFMA, epilogue fused with x*out1 store.
// adjw bf16 copy lives in xcpre's ws slot (dead after k_conv).

typedef __attribute__((ext_vector_type(8))) short short8;
typedef __attribute__((ext_vector_type(4))) float f32x4;

__device__ __forceinline__ float sigm_(float x){ return 1.f/(1.f+__expf(-x)); }
__device__ __forceinline__ float silu_(float x){ return x/(1.f+__expf(-x)); }
__device__ __forceinline__ float gelu_(float x){ return 0.5f*x*(1.f+erff(x*0.7071067811865476f)); }
__device__ __forceinline__ float softplus_(float x){ return (x>20.f)?x:log1pf(__expf(x)); }

// K1: row means (over w) -> xh[b,c,h]; col means (over h) -> xw[b,c,w]
__global__ void k_means(const float* __restrict__ x, float* __restrict__ xh, float* __restrict__ xw){
  int bc = blockIdx.x;                    // b*128+c
  const float* xt = x + (size_t)bc*25600; // 160*160 tile
  int tid = threadIdx.x, wave = tid>>6, lane = tid&63;
  __shared__ float colpart[4][160];
  float cs0=0.f, cs1=0.f, cs2=0.f;
  for (int i=0;i<40;i++){
    int h = wave*40+i;
    const float* row = xt + h*160;
    float v0 = row[lane];
    float v1 = row[64+lane];
    float v2 = (lane<32)? row[128+lane] : 0.f;
    cs0+=v0; cs1+=v1; cs2+=v2;
    float r = v0+v1+v2;
    for (int off=32; off>0; off>>=1) r += __shfl_down(r, off, 64);
    if (lane==0) xh[bc*160+h] = r*(1.f/160.f);
  }
  colpart[wave][lane]    = cs0;
  colpart[wave][64+lane] = cs1;
  if (lane<32) colpart[wave][128+lane] = cs2;
  __syncthreads();
  if (tid<160){
    float s = colpart[0][tid]+colpart[1][tid]+colpart[2][tid]+colpart[3][tid];
    xw[bc*160+tid] = s*(1.f/160.f);
  }
}

// K2a: y trunk: conv1x1(C->8) + BN + gelu over p in [0,320)
__global__ void k_ybranch(const float* __restrict__ xh, const float* __restrict__ xw,
                          const float* __restrict__ w1, const float* __restrict__ b1,
                          const float* __restrict__ bg, const float* __restrict__ bb,
                          const float* __restrict__ bm, const float* __restrict__ bv,
                          float* __restrict__ ybuf){
  int gid = blockIdx.x*blockDim.x + threadIdx.x;
  if (gid >= 8*320) return;
  int b = gid/320, p = gid%320;
  const float* in = (p<160) ? (xh + (size_t)b*128*160 + p) : (xw + (size_t)b*128*160 + (p-160));
  float acc[8] = {0,0,0,0,0,0,0,0};
  for (int c=0;c<128;c++){
    float u = in[c*160];
    #pragma unroll
    for (int m=0;m<8;m++) acc[m] += w1[m*128+c]*u;
  }
  #pragma unroll
  for (int m=0;m<8;m++){
    float val = acc[m] + b1[m];
    val = (val - bm[m]) * rsqrtf(bv[m] + 1e-5f);
    val = val * bg[m] + bb[m];
    ybuf[(b*320+p)*8+m] = gelu_(val);
  }
}

// K2b: a_h[b,c,h], a_w[b,c,w]: conv1x1(8->C)
__global__ void k_ahw(const float* __restrict__ ybuf,
                      const float* __restrict__ wh, const float* __restrict__ bh,
                      const float* __restrict__ ww, const float* __restrict__ bw,
                      float* __restrict__ a_h, float* __restrict__ a_w){
  int gid = blockIdx.x*blockDim.x + threadIdx.x;
  if (gid >= 8*128*320) return;
  int p = gid%320; int c = (gid/320)%128; int b = gid/(320*128);
  const float* yv = ybuf + (size_t)(b*320+p)*8;
  const float* w = (p<160)? (wh + c*8) : (ww + c*8);
  float acc = (p<160)? bh[c] : bw[c];
  #pragma unroll
  for (int m=0;m<8;m++) acc += w[m]*yv[m];
  if (p<160) a_h[((size_t)(b*128+c))*160+p] = acc;
  else       a_w[((size_t)(b*128+c))*160+(p-160)] = acc;
}

// K3: mamba in-proj: xz[g,b,l,e] = sum_c u*in_w; e<256 -> xc_pre, else z
__global__ void k_inproj(const float* __restrict__ xh, const float* __restrict__ xw,
                         const float* __restrict__ inw0, const float* __restrict__ inw1,
                         float* __restrict__ xcpre, float* __restrict__ zb){
  int blk = blockIdx.x;                   // (g*8+b)*160 + l
  int g = blk/1280, rem = blk%1280, b = rem/160, l = rem%160;
  __shared__ float u[128];
  const float* src = (g==0)? xh : xw;
  if (threadIdx.x<128) u[threadIdx.x] = src[((size_t)(b*128+threadIdx.x))*160 + l];
  __syncthreads();
  const float* inw = (g==0)? inw0 : inw1;
  size_t outbase = (size_t)blk*256;
  for (int e = threadIdx.x; e < 512; e += 256){
    const float* wr = inw + e*128;
    float acc = 0.f;
    for (int c=0;c<128;c++) acc += wr[c]*u[c];
    if (e<256) xcpre[outbase+e] = acc;
    else       zb[outbase+e-256] = acc;
  }
}

// K4a: depthwise causal conv(k=4) + bias + silu
__global__ void k_conv(const float* __restrict__ xcpre,
                       const float* __restrict__ cw0, const float* __restrict__ cb0,
                       const float* __restrict__ cw1, const float* __restrict__ cb1,
                       float* __restrict__ xcb){
  int gid = blockIdx.x*blockDim.x + threadIdx.x;
  if (gid >= 2*8*160*256) return;
  int d = gid & 255; int t = gid >> 8; int l = t % 160; int gb = t / 160; int g = gb >> 3;
  const float* cw = ((g==0)? cw0 : cw1) + d*4;
  float acc = ((g==0)? cb0 : cb1)[d];
  const float* base = xcpre + (size_t)gb*160*256 + d;
  #pragma unroll
  for (int k=0;k<4;k++){
    int ls = l-3+k;
    if (ls>=0) acc += cw[k] * base[(size_t)ls*256];
  }
  xcb[gid] = silu_(acc);
}

// K_prep: adjw fp32 -> bf16 (32768 elems) into dead xcpre slot
__global__ void k_prep(const float* __restrict__ adjw, __hip_bfloat16* __restrict__ adjwb){
  int i = blockIdx.x*256 + threadIdx.x;
  if (i < 32768) adjwb[i] = __float2bfloat16(adjw[i]);
}

// K4b: x-proj: dbc[g,b,l,j<40] = sum_d xc * xproj[j,d]
__global__ void k_xproj(const float* __restrict__ xcb,
                        const float* __restrict__ xp0, const float* __restrict__ xp1,
                        float* __restrict__ dbc){
  int blk = blockIdx.x;                   // (g*8+b)*160 + l
  int g = blk/1280;
  __shared__ float xv[256];
  const float* src = xcb + (size_t)blk*256;
  for (int i=threadIdx.x;i<256;i+=64) xv[i] = src[i];
  __syncthreads();
  int j = threadIdx.x;
  if (j < 40){
    const float* w = ((g==0)? xp0 : xp1) + j*256;
    float acc = 0.f;
    for (int d=0;d<256;d++) acc += w[d]*xv[d];
    dbc[(size_t)blk*40 + j] = acc;
  }
}

// K4c: delta = softplus(dt @ dt_w^T + dt_b)
__global__ void k_delta(const float* __restrict__ dbc,
                        const float* __restrict__ dtw0, const float* __restrict__ dtb0,
                        const float* __restrict__ dtw1, const float* __restrict__ dtb1,
                        float* __restrict__ delta){
  int gid = blockIdx.x*blockDim.x + threadIdx.x;
  if (gid >= 2*8*160*256) return;
  int d = gid & 255; int t = gid >> 8; int gb = t/160; int g = gb>>3;
  const float* dv = dbc + (size_t)t*40;
  const float* w = ((g==0)? dtw0 : dtw1) + d*8;
  float acc = ((g==0)? dtb0 : dtb1)[d];
  #pragma unroll
  for (int r=0;r<8;r++) acc += w[r]*dv[r];
  delta[gid] = softplus_(acc);
}

// K5: selective scan. 16 lanes per d (one per state n).
__global__ void k_scan(const float* __restrict__ delta, const float* __restrict__ dbc,
                       const float* __restrict__ xcb, const float* __restrict__ zb,
                       const float* __restrict__ Alog0, const float* __restrict__ Alog1,
                       const float* __restrict__ D0, const float* __restrict__ D1,
                       float* __restrict__ ysb){
  int blk = blockIdx.x;        // 256 blocks: gb = blk>>4, dblk = blk&15
  int gb = blk >> 4, dblk = blk & 15, g = gb >> 3;
  int tid = threadIdx.x;
  int d = dblk*16 + (tid>>4);
  int n = tid & 15;
  const float* Alog = g? Alog1 : Alog0;
  const float* Dp   = g? D1 : D0;
  float A = -__expf(Alog[d*16+n]);
  float Dd = Dp[d];
  size_t base = (size_t)gb*160*256;
  const float* del = delta + base;
  const float* xc  = xcb + base;
  const float* zz  = zb + base;
  float* ys = ysb + base;
  const float* db = dbc + (size_t)gb*160*40;
  float h = 0.f;
  float dl = del[d], xcv = xc[d], zv = zz[d];
  float Bn = db[8+n], Cn = db[24+n];
  for (int l=0; l<160; l++){
    float dl2=0.f,xcv2=0.f,zv2=0.f,Bn2=0.f,Cn2=0.f;
    if (l<159){
      size_t o = (size_t)(l+1)*256 + d;
      dl2=del[o]; xcv2=xc[o]; zv2=zz[o];
      size_t o2 = (size_t)(l+1)*40;
      Bn2=db[o2+8+n]; Cn2=db[o2+24+n];
    }
    float dA = __expf(dl*A);
    h = dA*h + dl*Bn*xcv;
    float p = h*Cn;
    p += __shfl_xor(p,1,16); p += __shfl_xor(p,2,16);
    p += __shfl_xor(p,4,16); p += __shfl_xor(p,8,16);
    if (n==0){
      float yv = p + xcv*Dd;
      ys[(size_t)l*256+d] = yv * silu_(zv);
    }
    dl=dl2; xcv=xcv2; zv=zv2; Bn=Bn2; Cn=Cn2;
  }
}

// K6a: out-proj (256->128) + add a + sigmoid -> S[g,b,c,l]
__global__ void k_outproj(const float* __restrict__ ysb,
                          const float* __restrict__ ow0, const float* __restrict__ ow1,
                          const float* __restrict__ a_h, const float* __restrict__ a_w,
                          float* __restrict__ S){
  int blk = blockIdx.x;  // (g*8+b)*160 + l
  int g = blk/1280, rem = blk%1280, b = rem/160, l = rem%160;
  __shared__ float yv[256];
  const float* src = ysb + (size_t)blk*256;
  yv[threadIdx.x] = src[threadIdx.x];
  yv[threadIdx.x+128] = src[threadIdx.x+128];
  __syncthreads();
  int c = threadIdx.x;
  const float* w = ((g==0)? ow0 : ow1) + c*256;
  float acc = 0.f;
  for (int d=0;d<256;d++) acc += w[d]*yv[d];
  const float* a = (g==0)? a_h : a_w;
  float val = sigm_(acc + a[((size_t)(b*128+c))*160 + l]);
  S[((size_t)(g*8+b)*128 + c)*160 + l] = val;
}

// K6b: MLP layer1 + gelu -> t1[g,b,p,c]
__global__ void k_mlp1(const float* __restrict__ S,
                       const float* __restrict__ w1x, const float* __restrict__ b1x,
                       const float* __restrict__ w1y, const float* __restrict__ b1y,
                       float* __restrict__ t1){
  int blk = blockIdx.x;  // (g*8+b)*160 + p
  int g = blk/1280, rem = blk%1280, b = rem/160, p = rem%160;
  __shared__ float sv[128];
  sv[threadIdx.x] = S[((size_t)(g*8+b)*128 + threadIdx.x)*160 + p];
  __syncthreads();
  int o = threadIdx.x;
  const float* w = ((g==0)? w1x : w1y) + o*128;
  float acc = ((g==0)? b1x : b1y)[o];
  for (int c=0;c<128;c++) acc += w[c]*sv[c];
  t1[(size_t)blk*128 + o] = gelu_(acc);
}

// K6c: MLP layer2 -> Qx[b,c,h] (g=0), Qy[b,c,w] (g=1)
__global__ void k_mlp2(const float* __restrict__ t1,
                       const float* __restrict__ w2x, const float* __restrict__ b2x,
                       const float* __restrict__ w2y, const float* __restrict__ b2y,
                       float* __restrict__ Qx, float* __restrict__ Qy){
  int blk = blockIdx.x;
  int g = blk/1280, rem = blk%1280, b = rem/160, p = rem%160;
  __shared__ float tv[128];
  tv[threadIdx.x] = t1[(size_t)blk*128 + threadIdx.x];
  __syncthreads();
  int o = threadIdx.x;
  const float* w = ((g==0)? w2x : w2y) + o*128;
  float acc = ((g==0)? b2x : b2y)[o];
  for (int c=0;c<128;c++) acc += w[c]*tv[c];
  float* Q = (g==0)? Qx : Qy;
  Q[((size_t)(b*128+o))*160 + p] = acc;
}

// K7 (MFMA): out[b,o,h,w] = x[b,o,h,w] * sum_k adjw[o,k]*F[k]
// block = (b, h, whalf): GEMM M=128 (o), K=256, N=80 (w). 4 waves x {2 m-tiles x 5 n-tiles}.
__global__ __launch_bounds__(256) void k_final_mfma(
                       const float* __restrict__ x,
                       const float* __restrict__ a_h, const float* __restrict__ a_w,
                       const float* __restrict__ Qx, const float* __restrict__ Qy,
                       const __hip_bfloat16* __restrict__ adjwb, float* __restrict__ out){
  __shared__ __hip_bfloat16 F[80*264];   // [w][k], k padded 256->264 (bank-conflict-free b128)
  int blk = blockIdx.x;                  // b*320 + h*2 + whalf
  int b = blk/320; int rem = blk%320; int h = rem>>1; int wh = rem&1;
  int wbase = wh*80;
  int tid = threadIdx.x;

  // ---- staging: thread t = k; loop 80 w via float4 ----
  {
    int k = tid;
    float s;
    const float* rowptr;
    if (k < 128){
      s = sigm_(a_h[((size_t)(b*128+k))*160 + h]);
      rowptr = Qy + ((size_t)(b*128+k))*160 + wbase;
    } else {
      s = Qx[((size_t)(b*128+k-128))*160 + h];
      rowptr = a_w + ((size_t)(b*128+k-128))*160 + wbase;
    }
    const float4* rp4 = (const float4*)rowptr;
    #pragma unroll 4
    for (int u=0; u<20; u++){
      float4 v = rp4[u];
      float f0,f1,f2,f3;
      if (k < 128){ f0=s*v.x; f1=s*v.y; f2=s*v.z; f3=s*v.w; }
      else { f0=s*sigm_(v.x); f1=s*sigm_(v.y); f2=s*sigm_(v.z); f3=s*sigm_(v.w); }
      int wr = u*4;
      F[(wr+0)*264 + k] = __float2bfloat16(f0);
      F[(wr+1)*264 + k] = __float2bfloat16(f1);
      F[(wr+2)*264 + k] = __float2bfloat16(f2);
      F[(wr+3)*264 + k] = __float2bfloat16(f3);
    }
  }
  __syncthreads();

  int wid = tid>>6, lane = tid&63, quad = lane>>4, l16 = lane&15;
  // ---- A fragments: wave wid owns m-tiles 2*wid, 2*wid+1 ----
  short8 afrag[2][8];
  #pragma unroll
  for (int i=0;i<2;i++){
    int mrow = (wid*2+i)*16 + l16;                 // o row
    const __hip_bfloat16* ap = adjwb + (size_t)mrow*256 + quad*8;
    #pragma unroll
    for (int kc=0;kc<8;kc++) afrag[i][kc] = *(const short8*)(ap + kc*32);
  }

  // ---- 5 n-tiles of 16 w ----
  for (int nt=0; nt<5; nt++){
    f32x4 acc0 = {0.f,0.f,0.f,0.f}, acc1 = {0.f,0.f,0.f,0.f};
    const __hip_bfloat16* bp = &F[(nt*16 + l16)*264 + quad*8];
    #pragma unroll
    for (int kc=0;kc<8;kc++){
      short8 bf = *(const short8*)(bp + kc*32);
      acc0 = __builtin_amdgcn_mfma_f32_16x16x32_bf16(afrag[0][kc], bf, acc0, 0,0,0);
      acc1 = __builtin_amdgcn_mfma_f32_16x16x32_bf16(afrag[1][kc], bf, acc1, 0,0,0);
    }
    int w = wbase + nt*16 + l16;                   // C col = lane&15
    #pragma unroll
    for (int i=0;i<2;i++){
      f32x4 a = i? acc1 : acc0;
      int ob = (wid*2+i)*16 + quad*4;              // C row = quad*4 + reg
      #pragma unroll
      for (int r=0;r<4;r++){
        size_t idx = (((size_t)(b*128+ob+r))*160 + h)*160 + w;
        out[idx] = x[idx] * a[r];
      }
    }
  }
}

extern "C" void kernel_launch(void* const* d_in, const int* in_sizes, int n_in,
                              void* d_out, int out_size, void* d_ws, size_t ws_size,
                              hipStream_t stream) {
  #define W(i) ((const float*)d_in[i])
  const float* X = W(0);
  float* ws = (float*)d_ws;
  float* xh    = ws;               // 163840
  float* xw    = xh    + 163840;   // 163840
  float* ybuf  = xw    + 163840;   // 20480
  float* ah    = ybuf  + 20480;    // 163840
  float* aw    = ah    + 163840;   // 163840
  float* xcpre = aw    + 163840;   // 655360 (dead after k_conv; adjwb aliases it)
  float* zb    = xcpre + 655360;   // 655360
  float* xcb   = zb    + 655360;   // 655360
  float* dbc   = xcb   + 655360;   // 102400
  float* delta = dbc   + 102400;   // 655360
  float* ysb   = delta + 655360;   // 655360
  float* S     = ysb   + 655360;   // 327680
  float* t1    = S     + 327680;   // 327680
  float* Qx    = t1    + 327680;   // 163840
  float* Qy    = Qx    + 163840;   // 163840
  __hip_bfloat16* adjwb = (__hip_bfloat16*)xcpre;  // 32768 bf16 = 64KB, reuses dead slot

  k_means  <<<1024, 256, 0, stream>>>(X, xh, xw);
  k_ybranch<<<10,   256, 0, stream>>>(xh, xw, W(1), W(2), W(3), W(4), W(5), W(6), ybuf);
  k_ahw    <<<1280, 256, 0, stream>>>(ybuf, W(7), W(8), W(9), W(10), ah, aw);
  k_inproj <<<2560, 256, 0, stream>>>(xh, xw, W(20), W(29), xcpre, zb);
  k_conv   <<<2560, 256, 0, stream>>>(xcpre, W(21), W(22), W(30), W(31), xcb);
  k_prep   <<<128,  256, 0, stream>>>(W(19), adjwb);   // after k_conv (xcpre dead)
  k_xproj  <<<2560, 64,  0, stream>>>(xcb, W(23), W(32), dbc);
  k_delta  <<<2560, 256, 0, stream>>>(dbc, W(24), W(25), W(33), W(34), delta);
  k_scan   <<<256,  256, 0, stream>>>(delta, dbc, xcb, zb, W(26), W(35), W(27), W(36), ysb);
  k_outproj<<<2560, 128, 0, stream>>>(ysb, W(28), W(37), ah, aw, S);
  k_mlp1   <<<2560, 128, 0, stream>>>(S, W(11), W(12), W(15), W(16), t1);
  k_mlp2   <<<2560, 128, 0, stream>>>(t1, W(13), W(14), W(17), W(18), Qx, Qy);
  k_final_mfma<<<2560, 256, 0, stream>>>(X, ah, aw, Qx, Qy, adjwb, (float*)d_out);
  #undef W
}

// Round 4
// 561.123 us; speedup vs baseline: 2.6018x; 1.1625x over previous
//
#include <hip/hip_runtime.h>
#include <hip/hip_bf16.h>
#include <math.h>

// EfficientMambaAttention, round 4: kill the latency-bound projection kernels.
// - k_inproj/k_xproj: l-tiled blocks, activations in LDS (broadcast), weights
//   register-tiled -> weight L2 traffic /tile, VALU-dense fp32.
// - k_post fuses outproj+mlp1+mlp2 (S,t1 stay in LDS; only Qx/Qy hit HBM).
// - k_delta folded into k_scan (softplus/exp computed one step ahead of h-chain).
// - k_means uses float4 row loads.
// - k_final stays MFMA bf16 (round-3 win).

typedef __attribute__((ext_vector_type(8))) short short8;
typedef __attribute__((ext_vector_type(4))) float f32x4;

__device__ __forceinline__ float sigm_(float x){ return 1.f/(1.f+__expf(-x)); }
__device__ __forceinline__ float silu_(float x){ return x/(1.f+__expf(-x)); }
__device__ __forceinline__ float gelu_(float x){ return 0.5f*x*(1.f+erff(x*0.7071067811865476f)); }
__device__ __forceinline__ float softplus_(float x){ return (x>20.f)?x:log1pf(__expf(x)); }

// K1: row means (over w) -> xh[b,c,h]; col means (over h) -> xw[b,c,w]. float4 loads.
__global__ void k_means(const float* __restrict__ x, float* __restrict__ xh, float* __restrict__ xw){
  int bc = blockIdx.x;                    // b*128+c
  const float* xt = x + (size_t)bc*25600; // 160*160 tile
  int tid = threadIdx.x, wave = tid>>6, lane = tid&63;
  __shared__ float4 colpart[4][40];
  float csx=0.f, csy=0.f, csz=0.f, csw=0.f;
  for (int i=0;i<40;i++){
    int h = wave*40+i;
    float4 v = make_float4(0.f,0.f,0.f,0.f);
    if (lane<40) v = ((const float4*)(xt + h*160))[lane];
    csx+=v.x; csy+=v.y; csz+=v.z; csw+=v.w;
    float r = v.x+v.y+v.z+v.w;
    for (int off=32; off>0; off>>=1) r += __shfl_down(r, off, 64);
    if (lane==0) xh[(size_t)bc*160+h] = r*(1.f/160.f);
  }
  if (lane<40) colpart[wave][lane] = make_float4(csx,csy,csz,csw);
  __syncthreads();
  if (tid<40){
    float4 a=colpart[0][tid], b=colpart[1][tid], c=colpart[2][tid], d=colpart[3][tid];
    float4 s = make_float4((a.x+b.x+c.x+d.x)*(1.f/160.f), (a.y+b.y+c.y+d.y)*(1.f/160.f),
                           (a.z+b.z+c.z+d.z)*(1.f/160.f), (a.w+b.w+c.w+d.w)*(1.f/160.f));
    ((float4*)(xw + (size_t)bc*160))[tid] = s;
  }
}

// K2a: y trunk: conv1x1(C->8) + BN + gelu over p in [0,320)
__global__ void k_ybranch(const float* __restrict__ xh, const float* __restrict__ xw,
                          const float* __restrict__ w1, const float* __restrict__ b1,
                          const float* __restrict__ bg, const float* __restrict__ bb,
                          const float* __restrict__ bm, const float* __restrict__ bv,
                          float* __restrict__ ybuf){
  int gid = blockIdx.x*blockDim.x + threadIdx.x;
  if (gid >= 8*320) return;
  int b = gid/320, p = gid%320;
  const float* in = (p<160) ? (xh + (size_t)b*128*160 + p) : (xw + (size_t)b*128*160 + (p-160));
  float acc[8] = {0,0,0,0,0,0,0,0};
  for (int c=0;c<128;c++){
    float u = in[c*160];
    #pragma unroll
    for (int m=0;m<8;m++) acc[m] += w1[m*128+c]*u;
  }
  #pragma unroll
  for (int m=0;m<8;m++){
    float val = acc[m] + b1[m];
    val = (val - bm[m]) * rsqrtf(bv[m] + 1e-5f);
    val = val * bg[m] + bb[m];
    ybuf[(b*320+p)*8+m] = gelu_(val);
  }
}

// K2b: a_h[b,c,h], a_w[b,c,w]: conv1x1(8->C)
__global__ void k_ahw(const float* __restrict__ ybuf,
                      const float* __restrict__ wh, const float* __restrict__ bh,
                      const float* __restrict__ ww, const float* __restrict__ bw,
                      float* __restrict__ a_h, float* __restrict__ a_w){
  int gid = blockIdx.x*blockDim.x + threadIdx.x;
  if (gid >= 8*128*320) return;
  int p = gid%320; int c = (gid/320)%128; int b = gid/(320*128);
  const float* yv = ybuf + (size_t)(b*320+p)*8;
  const float* w = (p<160)? (wh + c*8) : (ww + c*8);
  float acc = (p<160)? bh[c] : bw[c];
  #pragma unroll
  for (int m=0;m<8;m++) acc += w[m]*yv[m];
  if (p<160) a_h[((size_t)(b*128+c))*160+p] = acc;
  else       a_w[((size_t)(b*128+c))*160+(p-160)] = acc;
}

// K3: in-proj, l-tiled. block=(g,b,lt of 8), 256 thr: thread owns e and e+256.
__global__ __launch_bounds__(256) void k_inproj(
                         const float* __restrict__ xh, const float* __restrict__ xw,
                         const float* __restrict__ inw0, const float* __restrict__ inw1,
                         float* __restrict__ xcpre, float* __restrict__ zb){
  __shared__ float uS[8][128];
  int blk = blockIdx.x;                   // 2*8*20 = 320
  int g = blk/160, rem = blk%160, b = rem/20, lt = rem%20, lbase = lt*8;
  int t = threadIdx.x;
  const float* src = (g==0)? xh : xw;
  {
    int c = t>>1, lh = t&1;
    float4 v = *(const float4*)(src + ((size_t)(b*128+c))*160 + lbase + lh*4);
    uS[lh*4+0][c]=v.x; uS[lh*4+1][c]=v.y; uS[lh*4+2][c]=v.z; uS[lh*4+3][c]=v.w;
  }
  __syncthreads();
  const float* inw = (g==0)? inw0 : inw1;
  const float* w0p = inw + (size_t)t*128;
  const float* w1p = inw + (size_t)(t+256)*128;
  float acc0[8]={0,0,0,0,0,0,0,0}, acc1[8]={0,0,0,0,0,0,0,0};
  for (int ct=0; ct<16; ct++){
    float4 wa = *(const float4*)(w0p + ct*8);
    float4 wb = *(const float4*)(w0p + ct*8 + 4);
    float4 wc = *(const float4*)(w1p + ct*8);
    float4 wd = *(const float4*)(w1p + ct*8 + 4);
    #pragma unroll
    for (int l=0;l<8;l++){
      float4 ua = *(const float4*)&uS[l][ct*8];
      float4 ub = *(const float4*)&uS[l][ct*8+4];
      acc0[l] += wa.x*ua.x + wa.y*ua.y + wa.z*ua.z + wa.w*ua.w
               + wb.x*ub.x + wb.y*ub.y + wb.z*ub.z + wb.w*ub.w;
      acc1[l] += wc.x*ua.x + wc.y*ua.y + wc.z*ua.z + wc.w*ua.w
               + wd.x*ub.x + wd.y*ub.y + wd.z*ub.z + wd.w*ub.w;
    }
  }
  size_t ob = ((size_t)(g*8+b)*160 + lbase)*256;
  #pragma unroll
  for (int l=0;l<8;l++){
    xcpre[ob + (size_t)l*256 + t] = acc0[l];
    zb   [ob + (size_t)l*256 + t] = acc1[l];
  }
}

// K4a: depthwise causal conv(k=4) + bias + silu
__global__ void k_conv(const float* __restrict__ xcpre,
                       const float* __restrict__ cw0, const float* __restrict__ cb0,
                       const float* __restrict__ cw1, const float* __restrict__ cb1,
                       float* __restrict__ xcb){
  int gid = blockIdx.x*blockDim.x + threadIdx.x;
  if (gid >= 2*8*160*256) return;
  int d = gid & 255; int t = gid >> 8; int l = t % 160; int gb = t / 160; int g = gb >> 3;
  const float* cw = ((g==0)? cw0 : cw1) + d*4;
  float acc = ((g==0)? cb0 : cb1)[d];
  const float* base = xcpre + (size_t)gb*160*256 + d;
  #pragma unroll
  for (int k=0;k<4;k++){
    int ls = l-3+k;
    if (ls>=0) acc += cw[k] * base[(size_t)ls*256];
  }
  xcb[gid] = silu_(acc);
}

// K_prep: adjw fp32 -> bf16 (32768 elems) into dead xcpre slot
__global__ void k_prep(const float* __restrict__ adjw, __hip_bfloat16* __restrict__ adjwb){
  int i = blockIdx.x*256 + threadIdx.x;
  if (i < 32768) adjwb[i] = __float2bfloat16(adjw[i]);
}

// K4b: x-proj, l-tiled. block=(g,b,lt of 32), 256 thr = 32 l x 8 s, 5 j per thread.
__global__ __launch_bounds__(256) void k_xproj(
                        const float* __restrict__ xcb,
                        const float* __restrict__ xp0, const float* __restrict__ xp1,
                        float* __restrict__ dbc){
  __shared__ float xv[32][260];
  int blk = blockIdx.x;                   // 2*8*5 = 80
  int g = blk/40, rem = blk%40, b = rem/5, lt = rem%5, lbase = lt*32;
  int t = threadIdx.x;
  size_t base = ((size_t)(g*8+b)*160 + lbase)*256;
  for (int i=t; i<8192; i+=256){ int l=i>>8, d=i&255; xv[l][d] = xcb[base+i]; }
  __syncthreads();
  int l = t>>3, s = t&7;
  const float* xp = (g==0)? xp0 : xp1;
  size_t orow = ((size_t)(g*8+b)*160 + lbase + l)*40;
  for (int q=0;q<5;q++){
    int j = s + q*8;
    const float* w = xp + j*256;
    float acc=0.f;
    for (int dd=0; dd<256; dd+=8){
      float4 wa = *(const float4*)(w+dd);
      float4 wb = *(const float4*)(w+dd+4);
      float4 ua = *(const float4*)&xv[l][dd];
      float4 ub = *(const float4*)&xv[l][dd+4];
      acc += wa.x*ua.x + wa.y*ua.y + wa.z*ua.z + wa.w*ua.w
           + wb.x*ub.x + wb.y*ub.y + wb.z*ub.z + wb.w*ub.w;
    }
    dbc[orow + j] = acc;
  }
}

// K5: selective scan with fused delta (softplus(dt.dtw+b)). 16 lanes per d (one per n).
// delta/exp computed one step ahead -> h-chain is a single fma per step.
__global__ __launch_bounds__(256) void k_scan(
                       const float* __restrict__ dbc,
                       const float* __restrict__ xcb, const float* __restrict__ zb,
                       const float* __restrict__ dtw0, const float* __restrict__ dtb0,
                       const float* __restrict__ dtw1, const float* __restrict__ dtb1,
                       const float* __restrict__ Alog0, const float* __restrict__ Alog1,
                       const float* __restrict__ D0, const float* __restrict__ D1,
                       float* __restrict__ ysb){
  int blk = blockIdx.x;        // 256 blocks: gb = blk>>4, dblk = blk&15
  int gb = blk >> 4, dblk = blk & 15, g = gb >> 3;
  int tid = threadIdx.x;
  int d = dblk*16 + (tid>>4);
  int n = tid & 15;
  const float* dtw = ((g==0)? dtw0 : dtw1) + d*8;
  float4 wA = *(const float4*)dtw;
  float4 wB = *(const float4*)(dtw+4);
  float bias = ((g==0)? dtb0 : dtb1)[d];
  float A = -__expf(((g==0)? Alog0 : Alog1)[d*16+n]);
  float Dd = ((g==0)? D0 : D1)[d];
  size_t base = (size_t)gb*160*256;
  const float* db = dbc + (size_t)gb*160*40;

  float dA_c=0.f, dBu_c=0.f, Cn_c=0.f, xcv_c=0.f, zv_c=0.f;
  {
    const float* r = db;
    float4 r0 = *(const float4*)r;
    float4 r1 = *(const float4*)(r+4);
    float dt = bias + wA.x*r0.x+wA.y*r0.y+wA.z*r0.z+wA.w*r0.w
                    + wB.x*r1.x+wB.y*r1.y+wB.z*r1.z+wB.w*r1.w;
    float delta = softplus_(dt);
    xcv_c = xcb[base + d];
    zv_c  = zb [base + d];
    float Bn = r[8+n]; Cn_c = r[24+n];
    dA_c = __expf(delta*A);
    dBu_c = delta*Bn*xcv_c;
  }
  float h = 0.f;
  for (int l=0; l<160; l++){
    float dA_n=0.f, dBu_n=0.f, Cn_n=0.f, xcv_n=0.f, zv_n=0.f;
    if (l<159){
      const float* r = db + (size_t)(l+1)*40;
      float4 r0 = *(const float4*)r;
      float4 r1 = *(const float4*)(r+4);
      float dt = bias + wA.x*r0.x+wA.y*r0.y+wA.z*r0.z+wA.w*r0.w
                      + wB.x*r1.x+wB.y*r1.y+wB.z*r1.z+wB.w*r1.w;
      float delta = softplus_(dt);
      xcv_n = xcb[base + (size_t)(l+1)*256 + d];
      zv_n  = zb [base + (size_t)(l+1)*256 + d];
      float Bn = r[8+n]; Cn_n = r[24+n];
      dA_n = __expf(delta*A);
      dBu_n = delta*Bn*xcv_n;
    }
    h = dA_c*h + dBu_c;
    float p = h*Cn_c;
    p += __shfl_xor(p,1,16); p += __shfl_xor(p,2,16);
    p += __shfl_xor(p,4,16); p += __shfl_xor(p,8,16);
    if (n==0){
      ysb[base + (size_t)l*256 + d] = (p + xcv_c*Dd) * silu_(zv_c);
    }
    dA_c=dA_n; dBu_c=dBu_n; Cn_c=Cn_n; xcv_c=xcv_n; zv_c=zv_n;
  }
}

// K6: fused outproj(256->128)+sigmoid + mlp1(128->128,gelu) + mlp2(128->128).
// block=(g,b,lt of 10), 256 thr = 128 M x 2 K-halves, LDS combine. Writes Qx/Qy only.
__global__ __launch_bounds__(256) void k_post(
                       const float* __restrict__ ysb,
                       const float* __restrict__ ow0, const float* __restrict__ ow1,
                       const float* __restrict__ a_h, const float* __restrict__ a_w,
                       const float* __restrict__ w1x, const float* __restrict__ b1x,
                       const float* __restrict__ w1y, const float* __restrict__ b1y,
                       const float* __restrict__ w2x, const float* __restrict__ b2x,
                       const float* __restrict__ w2y, const float* __restrict__ b2y,
                       float* __restrict__ Qx, float* __restrict__ Qy){
  __shared__ float ysS[10][256];
  __shared__ float Sc[10][128];
  __shared__ float Sp[10][128];
  int blk = blockIdx.x;                   // 2*8*16 = 256
  int g = blk>>7, rem = blk&127, b = rem>>4, lt = rem&15, lbase = lt*10;
  int t = threadIdx.x; int c = t&127, kh = t>>7;
  size_t ybase = ((size_t)(g*8+b)*160 + lbase)*256;
  for (int i=t; i<2560; i+=256) ((float*)ysS)[i] = ysb[ybase+i];
  __syncthreads();
  float acc[10];
  // ---- out-proj (K=256 split 2x128) ----
  {
    const float* w = ((g==0)? ow0 : ow1) + (size_t)c*256 + kh*128;
    #pragma unroll
    for (int l=0;l<10;l++) acc[l]=0.f;
    for (int ct=0; ct<16; ct++){
      float4 wa = *(const float4*)(w + ct*8);
      float4 wb = *(const float4*)(w + ct*8 + 4);
      #pragma unroll
      for (int l=0;l<10;l++){
        float4 ua = *(const float4*)&ysS[l][kh*128+ct*8];
        float4 ub = *(const float4*)&ysS[l][kh*128+ct*8+4];
        acc[l] += wa.x*ua.x + wa.y*ua.y + wa.z*ua.z + wa.w*ua.w
                + wb.x*ub.x + wb.y*ub.y + wb.z*ub.z + wb.w*ub.w;
      }
    }
  }
  if (kh==1){ for (int l=0;l<10;l++) Sc[l][c] = acc[l]; }
  __syncthreads();
  if (kh==0){
    const float* a = ((g==0)? a_h : a_w) + ((size_t)(b*128+c))*160 + lbase;
    #pragma unroll
    for (int l=0;l<10;l++) Sp[l][c] = sigm_(acc[l] + Sc[l][c] + a[l]);
  }
  __syncthreads();
  // ---- mlp1 (K=128 split 2x64), gelu ----
  {
    const float* w = ((g==0)? w1x : w1y) + (size_t)c*128 + kh*64;
    #pragma unroll
    for (int l=0;l<10;l++) acc[l]=0.f;
    for (int ct=0; ct<8; ct++){
      float4 wa = *(const float4*)(w + ct*8);
      float4 wb = *(const float4*)(w + ct*8 + 4);
      #pragma unroll
      for (int l=0;l<10;l++){
        float4 ua = *(const float4*)&Sp[l][kh*64+ct*8];
        float4 ub = *(const float4*)&Sp[l][kh*64+ct*8+4];
        acc[l] += wa.x*ua.x + wa.y*ua.y + wa.z*ua.z + wa.w*ua.w
                + wb.x*ub.x + wb.y*ub.y + wb.z*ub.z + wb.w*ub.w;
      }
    }
  }
  if (kh==1){ for (int l=0;l<10;l++) Sc[l][c] = acc[l]; }
  __syncthreads();
  if (kh==0){
    float bb = ((g==0)? b1x : b1y)[c];
    float tv[10];
    #pragma unroll
    for (int l=0;l<10;l++) tv[l] = gelu_(bb + acc[l] + Sc[l][c]);
    __syncthreads();
    #pragma unroll
    for (int l=0;l<10;l++) Sp[l][c] = tv[l];
  } else {
    __syncthreads();
  }
  __syncthreads();
  // ---- mlp2 (K=128 split 2x64) ----
  {
    const float* w = ((g==0)? w2x : w2y) + (size_t)c*128 + kh*64;
    #pragma unroll
    for (int l=0;l<10;l++) acc[l]=0.f;
    for (int ct=0; ct<8; ct++){
      float4 wa = *(const float4*)(w + ct*8);
      float4 wb = *(const float4*)(w + ct*8 + 4);
      #pragma unroll
      for (int l=0;l<10;l++){
        float4 ua = *(const float4*)&Sp[l][kh*64+ct*8];
        float4 ub = *(const float4*)&Sp[l][kh*64+ct*8+4];
        acc[l] += wa.x*ua.x + wa.y*ua.y + wa.z*ua.z + wa.w*ua.w
                + wb.x*ub.x + wb.y*ub.y + wb.z*ub.z + wb.w*ub.w;
      }
    }
  }
  if (kh==1){ for (int l=0;l<10;l++) Sc[l][c] = acc[l]; }
  __syncthreads();
  if (kh==0){
    float bb = ((g==0)? b2x : b2y)[c];
    float* Q = (g==0)? Qx : Qy;
    size_t orow = ((size_t)(b*128+c))*160 + lbase;
    #pragma unroll
    for (int l=0;l<10;l++) Q[orow + l] = bb + acc[l] + Sc[l][c];
  }
}

// K7 (MFMA): out[b,o,h,w] = x[b,o,h,w] * sum_k adjw[o,k]*F[k]
__global__ __launch_bounds__(256) void k_final_mfma(
                       const float* __restrict__ x,
                       const float* __restrict__ a_h, const float* __restrict__ a_w,
                       const float* __restrict__ Qx, const float* __restrict__ Qy,
                       const __hip_bfloat16* __restrict__ adjwb, float* __restrict__ out){
  __shared__ __hip_bfloat16 F[80*264];   // [w][k], k padded 256->264
  int blk = blockIdx.x;                  // b*320 + h*2 + whalf
  int b = blk/320; int rem = blk%320; int h = rem>>1; int wh = rem&1;
  int wbase = wh*80;
  int tid = threadIdx.x;
  {
    int k = tid;
    float s;
    const float* rowptr;
    if (k < 128){
      s = sigm_(a_h[((size_t)(b*128+k))*160 + h]);
      rowptr = Qy + ((size_t)(b*128+k))*160 + wbase;
    } else {
      s = Qx[((size_t)(b*128+k-128))*160 + h];
      rowptr = a_w + ((size_t)(b*128+k-128))*160 + wbase;
    }
    const float4* rp4 = (const float4*)rowptr;
    #pragma unroll 4
    for (int u=0; u<20; u++){
      float4 v = rp4[u];
      float f0,f1,f2,f3;
      if (k < 128){ f0=s*v.x; f1=s*v.y; f2=s*v.z; f3=s*v.w; }
      else { f0=s*sigm_(v.x); f1=s*sigm_(v.y); f2=s*sigm_(v.z); f3=s*sigm_(v.w); }
      int wr = u*4;
      F[(wr+0)*264 + k] = __float2bfloat16(f0);
      F[(wr+1)*264 + k] = __float2bfloat16(f1);
      F[(wr+2)*264 + k] = __float2bfloat16(f2);
      F[(wr+3)*264 + k] = __float2bfloat16(f3);
    }
  }
  __syncthreads();

  int wid = tid>>6, lane = tid&63, quad = lane>>4, l16 = lane&15;
  short8 afrag[2][8];
  #pragma unroll
  for (int i=0;i<2;i++){
    int mrow = (wid*2+i)*16 + l16;
    const __hip_bfloat16* ap = adjwb + (size_t)mrow*256 + quad*8;
    #pragma unroll
    for (int kc=0;kc<8;kc++) afrag[i][kc] = *(const short8*)(ap + kc*32);
  }
  for (int nt=0; nt<5; nt++){
    f32x4 acc0 = {0.f,0.f,0.f,0.f}, acc1 = {0.f,0.f,0.f,0.f};
    const __hip_bfloat16* bp = &F[(nt*16 + l16)*264 + quad*8];
    #pragma unroll
    for (int kc=0;kc<8;kc++){
      short8 bf = *(const short8*)(bp + kc*32);
      acc0 = __builtin_amdgcn_mfma_f32_16x16x32_bf16(afrag[0][kc], bf, acc0, 0,0,0);
      acc1 = __builtin_amdgcn_mfma_f32_16x16x32_bf16(afrag[1][kc], bf, acc1, 0,0,0);
    }
    int w = wbase + nt*16 + l16;
    #pragma unroll
    for (int i=0;i<2;i++){
      f32x4 a = i? acc1 : acc0;
      int ob = (wid*2+i)*16 + quad*4;
      #pragma unroll
      for (int r=0;r<4;r++){
        size_t idx = (((size_t)(b*128+ob+r))*160 + h)*160 + w;
        out[idx] = x[idx] * a[r];
      }
    }
  }
}

extern "C" void kernel_launch(void* const* d_in, const int* in_sizes, int n_in,
                              void* d_out, int out_size, void* d_ws, size_t ws_size,
                              hipStream_t stream) {
  #define W(i) ((const float*)d_in[i])
  const float* X = W(0);
  float* ws = (float*)d_ws;
  float* xh    = ws;               // 163840
  float* xw    = xh    + 163840;   // 163840
  float* ybuf  = xw    + 163840;   // 20480
  float* ah    = ybuf  + 20480;    // 163840
  float* aw    = ah    + 163840;   // 163840
  float* xcpre = aw    + 163840;   // 655360 (dead after k_conv; adjwb aliases it)
  float* zb    = xcpre + 655360;   // 655360
  float* xcb   = zb    + 655360;   // 655360
  float* dbc   = xcb   + 655360;   // 102400
  float* ysb   = dbc   + 102400;   // 655360
  float* Qx    = ysb   + 655360;   // 163840
  float* Qy    = Qx    + 163840;   // 163840
  __hip_bfloat16* adjwb = (__hip_bfloat16*)xcpre;  // 64KB, reuses dead slot

  k_means  <<<1024, 256, 0, stream>>>(X, xh, xw);
  k_ybranch<<<10,   256, 0, stream>>>(xh, xw, W(1), W(2), W(3), W(4), W(5), W(6), ybuf);
  k_ahw    <<<1280, 256, 0, stream>>>(ybuf, W(7), W(8), W(9), W(10), ah, aw);
  k_inproj <<<320,  256, 0, stream>>>(xh, xw, W(20), W(29), xcpre, zb);
  k_conv   <<<2560, 256, 0, stream>>>(xcpre, W(21), W(22), W(30), W(31), xcb);
  k_prep   <<<128,  256, 0, stream>>>(W(19), adjwb);   // after k_conv (xcpre dead)
  k_xproj  <<<80,   256, 0, stream>>>(xcb, W(23), W(32), dbc);
  k_scan   <<<256,  256, 0, stream>>>(dbc, xcb, zb, W(24), W(25), W(33), W(34),
                                      W(26), W(35), W(27), W(36), ysb);
  k_post   <<<256,  256, 0, stream>>>(ysb, W(28), W(37), ah, aw,
                                      W(11), W(12), W(15), W(16),
                                      W(13), W(14), W(17), W(18), Qx, Qy);
  k_final_mfma<<<2560, 256, 0, stream>>>(X, ah, aw, Qx, Qy, adjwb, (float*)d_out);
  #undef W
}

// Round 5
// 478.397 us; speedup vs baseline: 3.0517x; 1.1729x over previous
//
#include <hip/hip_runtime.h>
#include <hip/hip_bf16.h>
#include <math.h>

// EfficientMambaAttention, round 5: k_scan restructured to LDS-resident scan.
// Phase 1 (parallel): stage xc/B/C + precompute delta into LDS (40KB).
// Phase 2 (sequential, x8 unroll): h-chain runs from LDS, batched reads.
// Phase 3: coalesced writeout * silu(z).
// Everything else unchanged from round 4.

typedef __attribute__((ext_vector_type(8))) short short8;
typedef __attribute__((ext_vector_type(4))) float f32x4;

__device__ __forceinline__ float sigm_(float x){ return 1.f/(1.f+__expf(-x)); }
__device__ __forceinline__ float silu_(float x){ return x/(1.f+__expf(-x)); }
__device__ __forceinline__ float gelu_(float x){ return 0.5f*x*(1.f+erff(x*0.7071067811865476f)); }
__device__ __forceinline__ float softplus_(float x){ return (x>20.f)?x:log1pf(__expf(x)); }

// K1: row means (over w) -> xh[b,c,h]; col means (over h) -> xw[b,c,w]. float4 loads.
__global__ void k_means(const float* __restrict__ x, float* __restrict__ xh, float* __restrict__ xw){
  int bc = blockIdx.x;                    // b*128+c
  const float* xt = x + (size_t)bc*25600; // 160*160 tile
  int tid = threadIdx.x, wave = tid>>6, lane = tid&63;
  __shared__ float4 colpart[4][40];
  float csx=0.f, csy=0.f, csz=0.f, csw=0.f;
  for (int i=0;i<40;i++){
    int h = wave*40+i;
    float4 v = make_float4(0.f,0.f,0.f,0.f);
    if (lane<40) v = ((const float4*)(xt + h*160))[lane];
    csx+=v.x; csy+=v.y; csz+=v.z; csw+=v.w;
    float r = v.x+v.y+v.z+v.w;
    for (int off=32; off>0; off>>=1) r += __shfl_down(r, off, 64);
    if (lane==0) xh[(size_t)bc*160+h] = r*(1.f/160.f);
  }
  if (lane<40) colpart[wave][lane] = make_float4(csx,csy,csz,csw);
  __syncthreads();
  if (tid<40){
    float4 a=colpart[0][tid], b=colpart[1][tid], c=colpart[2][tid], d=colpart[3][tid];
    float4 s = make_float4((a.x+b.x+c.x+d.x)*(1.f/160.f), (a.y+b.y+c.y+d.y)*(1.f/160.f),
                           (a.z+b.z+c.z+d.z)*(1.f/160.f), (a.w+b.w+c.w+d.w)*(1.f/160.f));
    ((float4*)(xw + (size_t)bc*160))[tid] = s;
  }
}

// K2a: y trunk: conv1x1(C->8) + BN + gelu over p in [0,320)
__global__ void k_ybranch(const float* __restrict__ xh, const float* __restrict__ xw,
                          const float* __restrict__ w1, const float* __restrict__ b1,
                          const float* __restrict__ bg, const float* __restrict__ bb,
                          const float* __restrict__ bm, const float* __restrict__ bv,
                          float* __restrict__ ybuf){
  int gid = blockIdx.x*blockDim.x + threadIdx.x;
  if (gid >= 8*320) return;
  int b = gid/320, p = gid%320;
  const float* in = (p<160) ? (xh + (size_t)b*128*160 + p) : (xw + (size_t)b*128*160 + (p-160));
  float acc[8] = {0,0,0,0,0,0,0,0};
  for (int c=0;c<128;c++){
    float u = in[c*160];
    #pragma unroll
    for (int m=0;m<8;m++) acc[m] += w1[m*128+c]*u;
  }
  #pragma unroll
  for (int m=0;m<8;m++){
    float val = acc[m] + b1[m];
    val = (val - bm[m]) * rsqrtf(bv[m] + 1e-5f);
    val = val * bg[m] + bb[m];
    ybuf[(b*320+p)*8+m] = gelu_(val);
  }
}

// K2b: a_h[b,c,h], a_w[b,c,w]: conv1x1(8->C)
__global__ void k_ahw(const float* __restrict__ ybuf,
                      const float* __restrict__ wh, const float* __restrict__ bh,
                      const float* __restrict__ ww, const float* __restrict__ bw,
                      float* __restrict__ a_h, float* __restrict__ a_w){
  int gid = blockIdx.x*blockDim.x + threadIdx.x;
  if (gid >= 8*128*320) return;
  int p = gid%320; int c = (gid/320)%128; int b = gid/(320*128);
  const float* yv = ybuf + (size_t)(b*320+p)*8;
  const float* w = (p<160)? (wh + c*8) : (ww + c*8);
  float acc = (p<160)? bh[c] : bw[c];
  #pragma unroll
  for (int m=0;m<8;m++) acc += w[m]*yv[m];
  if (p<160) a_h[((size_t)(b*128+c))*160+p] = acc;
  else       a_w[((size_t)(b*128+c))*160+(p-160)] = acc;
}

// K3: in-proj, l-tiled. block=(g,b,lt of 8), 256 thr: thread owns e and e+256.
__global__ __launch_bounds__(256) void k_inproj(
                         const float* __restrict__ xh, const float* __restrict__ xw,
                         const float* __restrict__ inw0, const float* __restrict__ inw1,
                         float* __restrict__ xcpre, float* __restrict__ zb){
  __shared__ float uS[8][128];
  int blk = blockIdx.x;                   // 2*8*20 = 320
  int g = blk/160, rem = blk%160, b = rem/20, lt = rem%20, lbase = lt*8;
  int t = threadIdx.x;
  const float* src = (g==0)? xh : xw;
  {
    int c = t>>1, lh = t&1;
    float4 v = *(const float4*)(src + ((size_t)(b*128+c))*160 + lbase + lh*4);
    uS[lh*4+0][c]=v.x; uS[lh*4+1][c]=v.y; uS[lh*4+2][c]=v.z; uS[lh*4+3][c]=v.w;
  }
  __syncthreads();
  const float* inw = (g==0)? inw0 : inw1;
  const float* w0p = inw + (size_t)t*128;
  const float* w1p = inw + (size_t)(t+256)*128;
  float acc0[8]={0,0,0,0,0,0,0,0}, acc1[8]={0,0,0,0,0,0,0,0};
  for (int ct=0; ct<16; ct++){
    float4 wa = *(const float4*)(w0p + ct*8);
    float4 wb = *(const float4*)(w0p + ct*8 + 4);
    float4 wc = *(const float4*)(w1p + ct*8);
    float4 wd = *(const float4*)(w1p + ct*8 + 4);
    #pragma unroll
    for (int l=0;l<8;l++){
      float4 ua = *(const float4*)&uS[l][ct*8];
      float4 ub = *(const float4*)&uS[l][ct*8+4];
      acc0[l] += wa.x*ua.x + wa.y*ua.y + wa.z*ua.z + wa.w*ua.w
               + wb.x*ub.x + wb.y*ub.y + wb.z*ub.z + wb.w*ub.w;
      acc1[l] += wc.x*ua.x + wc.y*ua.y + wc.z*ua.z + wc.w*ua.w
               + wd.x*ub.x + wd.y*ub.y + wd.z*ub.z + wd.w*ub.w;
    }
  }
  size_t ob = ((size_t)(g*8+b)*160 + lbase)*256;
  #pragma unroll
  for (int l=0;l<8;l++){
    xcpre[ob + (size_t)l*256 + t] = acc0[l];
    zb   [ob + (size_t)l*256 + t] = acc1[l];
  }
}

// K4a: depthwise causal conv(k=4) + bias + silu
__global__ void k_conv(const float* __restrict__ xcpre,
                       const float* __restrict__ cw0, const float* __restrict__ cb0,
                       const float* __restrict__ cw1, const float* __restrict__ cb1,
                       float* __restrict__ xcb){
  int gid = blockIdx.x*blockDim.x + threadIdx.x;
  if (gid >= 2*8*160*256) return;
  int d = gid & 255; int t = gid >> 8; int l = t % 160; int gb = t / 160; int g = gb >> 3;
  const float* cw = ((g==0)? cw0 : cw1) + d*4;
  float acc = ((g==0)? cb0 : cb1)[d];
  const float* base = xcpre + (size_t)gb*160*256 + d;
  #pragma unroll
  for (int k=0;k<4;k++){
    int ls = l-3+k;
    if (ls>=0) acc += cw[k] * base[(size_t)ls*256];
  }
  xcb[gid] = silu_(acc);
}

// K_prep: adjw fp32 -> bf16 (32768 elems) into dead xcpre slot
__global__ void k_prep(const float* __restrict__ adjw, __hip_bfloat16* __restrict__ adjwb){
  int i = blockIdx.x*256 + threadIdx.x;
  if (i < 32768) adjwb[i] = __float2bfloat16(adjw[i]);
}

// K4b: x-proj, l-tiled. block=(g,b,lt of 32), 256 thr = 32 l x 8 s, 5 j per thread.
__global__ __launch_bounds__(256) void k_xproj(
                        const float* __restrict__ xcb,
                        const float* __restrict__ xp0, const float* __restrict__ xp1,
                        float* __restrict__ dbc){
  __shared__ float xv[32][260];
  int blk = blockIdx.x;                   // 2*8*5 = 80
  int g = blk/40, rem = blk%40, b = rem/5, lt = rem%5, lbase = lt*32;
  int t = threadIdx.x;
  size_t base = ((size_t)(g*8+b)*160 + lbase)*256;
  for (int i=t; i<8192; i+=256){ int l=i>>8, d=i&255; xv[l][d] = xcb[base+i]; }
  __syncthreads();
  int l = t>>3, s = t&7;
  const float* xp = (g==0)? xp0 : xp1;
  size_t orow = ((size_t)(g*8+b)*160 + lbase + l)*40;
  for (int q=0;q<5;q++){
    int j = s + q*8;
    const float* w = xp + j*256;
    float acc=0.f;
    for (int dd=0; dd<256; dd+=8){
      float4 wa = *(const float4*)(w+dd);
      float4 wb = *(const float4*)(w+dd+4);
      float4 ua = *(const float4*)&xv[l][dd];
      float4 ub = *(const float4*)&xv[l][dd+4];
      acc += wa.x*ua.x + wa.y*ua.y + wa.z*ua.z + wa.w*ua.w
           + wb.x*ub.x + wb.y*ub.y + wb.z*ub.z + wb.w*ub.w;
    }
    dbc[orow + j] = acc;
  }
}

// K5: selective scan, LDS-resident. 256 blocks: (gb, dblk of 16 d).
// Phase 1: stage xc + B/C + precompute delta (softplus(dt.w+b)) into LDS.
// Phase 2: scan from LDS, 8-step batched reads.
// Phase 3: coalesced writeout * silu(z).
__global__ __launch_bounds__(256) void k_scan(
                       const float* __restrict__ dbc,
                       const float* __restrict__ xcb, const float* __restrict__ zb,
                       const float* __restrict__ dtw0, const float* __restrict__ dtb0,
                       const float* __restrict__ dtw1, const float* __restrict__ dtb1,
                       const float* __restrict__ Alog0, const float* __restrict__ Alog1,
                       const float* __restrict__ D0, const float* __restrict__ D1,
                       float* __restrict__ ysb){
  __shared__ float dsS[160][16];   // delta[l][dloc]
  __shared__ float BS [160][16];   // B[l][n]
  __shared__ float CS [160][16];   // C[l][n]
  __shared__ float xcS[160][16];   // xc[l][dloc]
  __shared__ float yS [160][16];   // y (pre-silu-z) [l][dloc]
  int blk = blockIdx.x;            // gb = blk>>4 (16), dblk = blk&15
  int gb = blk >> 4, dblk = blk & 15, g = gb >> 3;
  int dbase = dblk*16;
  int t = threadIdx.x;
  size_t base = (size_t)gb*160*256;
  const float* db = dbc + (size_t)gb*6400;
  const float* dtwG = (g==0)? dtw0 : dtw1;
  const float* dtbG = (g==0)? dtb0 : dtb1;

  #pragma unroll
  for (int i=0;i<10;i++){
    int item = t + 256*i;          // 2560 = 160 l x 16
    int l = item>>4, c = item&15;
    const float* r = db + l*40;
    int d = dbase + c;
    const float* wt = dtwG + d*8;
    float4 w0 = *(const float4*)wt;
    float4 w1 = *(const float4*)(wt+4);
    float4 r0 = *(const float4*)r;
    float4 r1 = *(const float4*)(r+4);
    float dt = dtbG[d] + w0.x*r0.x+w0.y*r0.y+w0.z*r0.z+w0.w*r0.w
                       + w1.x*r1.x+w1.y*r1.y+w1.z*r1.z+w1.w*r1.w;
    dsS[l][c] = softplus_(dt);
    BS [l][c] = r[8+c];
    CS [l][c] = r[24+c];
    xcS[l][c] = xcb[base + (size_t)l*256 + dbase + c];
  }
  __syncthreads();

  int dloc = t>>4, n = t&15;
  int d = dbase + dloc;
  float A  = -__expf(((g==0)? Alog0 : Alog1)[d*16+n]);
  float Dd = ((g==0)? D0 : D1)[d];
  float h = 0.f;
  for (int lc=0; lc<160; lc+=8){
    float ds8[8], B8[8], C8[8], xc8[8];
    #pragma unroll
    for (int j=0;j<8;j++){
      ds8[j]=dsS[lc+j][dloc]; B8[j]=BS[lc+j][n];
      C8[j]=CS[lc+j][n];      xc8[j]=xcS[lc+j][dloc];
    }
    #pragma unroll
    for (int j=0;j<8;j++){
      float dA = __expf(ds8[j]*A);
      h = dA*h + ds8[j]*B8[j]*xc8[j];
      float p = h*C8[j];
      p += __shfl_xor(p,1,16); p += __shfl_xor(p,2,16);
      p += __shfl_xor(p,4,16); p += __shfl_xor(p,8,16);
      if (n==0) yS[lc+j][dloc] = p + xc8[j]*Dd;
    }
  }
  __syncthreads();

  #pragma unroll
  for (int i=0;i<10;i++){
    int item = t + 256*i;
    int l = item>>4, c = item&15;
    size_t gi = base + (size_t)l*256 + dbase + c;
    ysb[gi] = yS[l][c] * silu_(zb[gi]);
  }
}

// K6: fused outproj(256->128)+sigmoid + mlp1(128->128,gelu) + mlp2(128->128).
__global__ __launch_bounds__(256) void k_post(
                       const float* __restrict__ ysb,
                       const float* __restrict__ ow0, const float* __restrict__ ow1,
                       const float* __restrict__ a_h, const float* __restrict__ a_w,
                       const float* __restrict__ w1x, const float* __restrict__ b1x,
                       const float* __restrict__ w1y, const float* __restrict__ b1y,
                       const float* __restrict__ w2x, const float* __restrict__ b2x,
                       const float* __restrict__ w2y, const float* __restrict__ b2y,
                       float* __restrict__ Qx, float* __restrict__ Qy){
  __shared__ float ysS[10][256];
  __shared__ float Sc[10][128];
  __shared__ float Sp[10][128];
  int blk = blockIdx.x;                   // 2*8*16 = 256
  int g = blk>>7, rem = blk&127, b = rem>>4, lt = rem&15, lbase = lt*10;
  int t = threadIdx.x; int c = t&127, kh = t>>7;
  size_t ybase = ((size_t)(g*8+b)*160 + lbase)*256;
  for (int i=t; i<2560; i+=256) ((float*)ysS)[i] = ysb[ybase+i];
  __syncthreads();
  float acc[10];
  // ---- out-proj (K=256 split 2x128) ----
  {
    const float* w = ((g==0)? ow0 : ow1) + (size_t)c*256 + kh*128;
    #pragma unroll
    for (int l=0;l<10;l++) acc[l]=0.f;
    for (int ct=0; ct<16; ct++){
      float4 wa = *(const float4*)(w + ct*8);
      float4 wb = *(const float4*)(w + ct*8 + 4);
      #pragma unroll
      for (int l=0;l<10;l++){
        float4 ua = *(const float4*)&ysS[l][kh*128+ct*8];
        float4 ub = *(const float4*)&ysS[l][kh*128+ct*8+4];
        acc[l] += wa.x*ua.x + wa.y*ua.y + wa.z*ua.z + wa.w*ua.w
                + wb.x*ub.x + wb.y*ub.y + wb.z*ub.z + wb.w*ub.w;
      }
    }
  }
  if (kh==1){ for (int l=0;l<10;l++) Sc[l][c] = acc[l]; }
  __syncthreads();
  if (kh==0){
    const float* a = ((g==0)? a_h : a_w) + ((size_t)(b*128+c))*160 + lbase;
    #pragma unroll
    for (int l=0;l<10;l++) Sp[l][c] = sigm_(acc[l] + Sc[l][c] + a[l]);
  }
  __syncthreads();
  // ---- mlp1 (K=128 split 2x64), gelu ----
  {
    const float* w = ((g==0)? w1x : w1y) + (size_t)c*128 + kh*64;
    #pragma unroll
    for (int l=0;l<10;l++) acc[l]=0.f;
    for (int ct=0; ct<8; ct++){
      float4 wa = *(const float4*)(w + ct*8);
      float4 wb = *(const float4*)(w + ct*8 + 4);
      #pragma unroll
      for (int l=0;l<10;l++){
        float4 ua = *(const float4*)&Sp[l][kh*64+ct*8];
        float4 ub = *(const float4*)&Sp[l][kh*64+ct*8+4];
        acc[l] += wa.x*ua.x + wa.y*ua.y + wa.z*ua.z + wa.w*ua.w
                + wb.x*ub.x + wb.y*ub.y + wb.z*ub.z + wb.w*ub.w;
      }
    }
  }
  if (kh==1){ for (int l=0;l<10;l++) Sc[l][c] = acc[l]; }
  __syncthreads();
  if (kh==0){
    float bb = ((g==0)? b1x : b1y)[c];
    float tv[10];
    #pragma unroll
    for (int l=0;l<10;l++) tv[l] = gelu_(bb + acc[l] + Sc[l][c]);
    __syncthreads();
    #pragma unroll
    for (int l=0;l<10;l++) Sp[l][c] = tv[l];
  } else {
    __syncthreads();
  }
  __syncthreads();
  // ---- mlp2 (K=128 split 2x64) ----
  {
    const float* w = ((g==0)? w2x : w2y) + (size_t)c*128 + kh*64;
    #pragma unroll
    for (int l=0;l<10;l++) acc[l]=0.f;
    for (int ct=0; ct<8; ct++){
      float4 wa = *(const float4*)(w + ct*8);
      float4 wb = *(const float4*)(w + ct*8 + 4);
      #pragma unroll
      for (int l=0;l<10;l++){
        float4 ua = *(const float4*)&Sp[l][kh*64+ct*8];
        float4 ub = *(const float4*)&Sp[l][kh*64+ct*8+4];
        acc[l] += wa.x*ua.x + wa.y*ua.y + wa.z*ua.z + wa.w*ua.w
                + wb.x*ub.x + wb.y*ub.y + wb.z*ub.z + wb.w*ub.w;
      }
    }
  }
  if (kh==1){ for (int l=0;l<10;l++) Sc[l][c] = acc[l]; }
  __syncthreads();
  if (kh==0){
    float bb = ((g==0)? b2x : b2y)[c];
    float* Q = (g==0)? Qx : Qy;
    size_t orow = ((size_t)(b*128+c))*160 + lbase;
    #pragma unroll
    for (int l=0;l<10;l++) Q[orow + l] = bb + acc[l] + Sc[l][c];
  }
}

// K7 (MFMA): out[b,o,h,w] = x[b,o,h,w] * sum_k adjw[o,k]*F[k]
__global__ __launch_bounds__(256) void k_final_mfma(
                       const float* __restrict__ x,
                       const float* __restrict__ a_h, const float* __restrict__ a_w,
                       const float* __restrict__ Qx, const float* __restrict__ Qy,
                       const __hip_bfloat16* __restrict__ adjwb, float* __restrict__ out){
  __shared__ __hip_bfloat16 F[80*264];   // [w][k], k padded 256->264
  int blk = blockIdx.x;                  // b*320 + h*2 + whalf
  int b = blk/320; int rem = blk%320; int h = rem>>1; int wh = rem&1;
  int wbase = wh*80;
  int tid = threadIdx.x;
  {
    int k = tid;
    float s;
    const float* rowptr;
    if (k < 128){
      s = sigm_(a_h[((size_t)(b*128+k))*160 + h]);
      rowptr = Qy + ((size_t)(b*128+k))*160 + wbase;
    } else {
      s = Qx[((size_t)(b*128+k-128))*160 + h];
      rowptr = a_w + ((size_t)(b*128+k-128))*160 + wbase;
    }
    const float4* rp4 = (const float4*)rowptr;
    #pragma unroll 4
    for (int u=0; u<20; u++){
      float4 v = rp4[u];
      float f0,f1,f2,f3;
      if (k < 128){ f0=s*v.x; f1=s*v.y; f2=s*v.z; f3=s*v.w; }
      else { f0=s*sigm_(v.x); f1=s*sigm_(v.y); f2=s*sigm_(v.z); f3=s*sigm_(v.w); }
      int wr = u*4;
      F[(wr+0)*264 + k] = __float2bfloat16(f0);
      F[(wr+1)*264 + k] = __float2bfloat16(f1);
      F[(wr+2)*264 + k] = __float2bfloat16(f2);
      F[(wr+3)*264 + k] = __float2bfloat16(f3);
    }
  }
  __syncthreads();

  int wid = tid>>6, lane = tid&63, quad = lane>>4, l16 = lane&15;
  short8 afrag[2][8];
  #pragma unroll
  for (int i=0;i<2;i++){
    int mrow = (wid*2+i)*16 + l16;
    const __hip_bfloat16* ap = adjwb + (size_t)mrow*256 + quad*8;
    #pragma unroll
    for (int kc=0;kc<8;kc++) afrag[i][kc] = *(const short8*)(ap + kc*32);
  }
  for (int nt=0; nt<5; nt++){
    f32x4 acc0 = {0.f,0.f,0.f,0.f}, acc1 = {0.f,0.f,0.f,0.f};
    const __hip_bfloat16* bp = &F[(nt*16 + l16)*264 + quad*8];
    #pragma unroll
    for (int kc=0;kc<8;kc++){
      short8 bf = *(const short8*)(bp + kc*32);
      acc0 = __builtin_amdgcn_mfma_f32_16x16x32_bf16(afrag[0][kc], bf, acc0, 0,0,0);
      acc1 = __builtin_amdgcn_mfma_f32_16x16x32_bf16(afrag[1][kc], bf, acc1, 0,0,0);
    }
    int w = wbase + nt*16 + l16;
    #pragma unroll
    for (int i=0;i<2;i++){
      f32x4 a = i? acc1 : acc0;
      int ob = (wid*2+i)*16 + quad*4;
      #pragma unroll
      for (int r=0;r<4;r++){
        size_t idx = (((size_t)(b*128+ob+r))*160 + h)*160 + w;
        out[idx] = x[idx] * a[r];
      }
    }
  }
}

extern "C" void kernel_launch(void* const* d_in, const int* in_sizes, int n_in,
                              void* d_out, int out_size, void* d_ws, size_t ws_size,
                              hipStream_t stream) {
  #define W(i) ((const float*)d_in[i])
  const float* X = W(0);
  float* ws = (float*)d_ws;
  float* xh    = ws;               // 163840
  float* xw    = xh    + 163840;   // 163840
  float* ybuf  = xw    + 163840;   // 20480
  float* ah    = ybuf  + 20480;    // 163840
  float* aw    = ah    + 163840;   // 163840
  float* xcpre = aw    + 163840;   // 655360 (dead after k_conv; adjwb aliases it)
  float* zb    = xcpre + 655360;   // 655360
  float* xcb   = zb    + 655360;   // 655360
  float* dbc   = xcb   + 655360;   // 102400
  float* ysb   = dbc   + 102400;   // 655360
  float* Qx    = ysb   + 655360;   // 163840
  float* Qy    = Qx    + 163840;   // 163840
  __hip_bfloat16* adjwb = (__hip_bfloat16*)xcpre;  // 64KB, reuses dead slot

  k_means  <<<1024, 256, 0, stream>>>(X, xh, xw);
  k_ybranch<<<10,   256, 0, stream>>>(xh, xw, W(1), W(2), W(3), W(4), W(5), W(6), ybuf);
  k_ahw    <<<1280, 256, 0, stream>>>(ybuf, W(7), W(8), W(9), W(10), ah, aw);
  k_inproj <<<320,  256, 0, stream>>>(xh, xw, W(20), W(29), xcpre, zb);
  k_conv   <<<2560, 256, 0, stream>>>(xcpre, W(21), W(22), W(30), W(31), xcb);
  k_prep   <<<128,  256, 0, stream>>>(W(19), adjwb);   // after k_conv (xcpre dead)
  k_xproj  <<<80,   256, 0, stream>>>(xcb, W(23), W(32), dbc);
  k_scan   <<<256,  256, 0, stream>>>(dbc, xcb, zb, W(24), W(25), W(33), W(34),
                                      W(26), W(35), W(27), W(36), ysb);
  k_post   <<<256,  256, 0, stream>>>(ysb, W(28), W(37), ah, aw,
                                      W(11), W(12), W(15), W(16),
                                      W(13), W(14), W(17), W(18), Qx, Qy);
  k_final_mfma<<<2560, 256, 0, stream>>>(X, ah, aw, Qx, Qy, adjwb, (float*)d_out);
  #undef W
}